// Round 8
// baseline (430.837 us; speedup 1.0000x reference)
//
#include <hip/hip_runtime.h>
#include <hip/hip_bf16.h>
#include <math.h>

typedef __hip_bfloat16 bf16;
typedef __attribute__((ext_vector_type(8))) short short8;
typedef __attribute__((ext_vector_type(4))) float f32x4;

#define BATCH   4
#define L_SEQ   2048
#define DMODEL  1024
#define DSTATE  16
#define DCONV   4
#define DINNER  2048
#define M_ROWS  (BATCH * L_SEQ)   // 8192

#define CHUNK   64
#define NCH     (L_SEQ / CHUNK)   // 32
#define PSTR    52                // P record: A_bar[16] B_bar[16] C[16] (pad4) = 208B
#define NX      33                // x_dbl columns
#define KSPL    8                 // K-split for the xdbl GEMM

__device__ __forceinline__ float b2f(bf16 v) { return __bfloat162float(v); }
__device__ __forceinline__ bf16  f2b(float v) { return __float2bfloat16(v); }
__device__ __forceinline__ float us2f(unsigned short u) {
    return __uint_as_float(((unsigned)u) << 16);
}
__device__ __forceinline__ float ldany(const void* p, int i, int f32) {
    return f32 ? ((const float*)p)[i] : b2f(((const bf16*)p)[i]);
}
__device__ __forceinline__ void load_lds16(const void* g, void* l) {
    __builtin_amdgcn_global_load_lds(
        (const __attribute__((address_space(1))) unsigned int*)g,
        (__attribute__((address_space(3))) unsigned int*)l, 16, 0, 0);
}

union V8 { float4 f4; unsigned short us[8]; };

// ---------------------------------------------------------------------------
// dtype detect + zero the chunk-delta accumulator S (pack_P atomicAdds into it)
// ---------------------------------------------------------------------------
__global__ void detect_dtype(const unsigned int* __restrict__ alog_bits,
                             int* __restrict__ flag, float* __restrict__ S)
{
    *flag = (alog_bits[0] == 0u) ? 1 : 0;
    for (int i = 0; i < BATCH * NCH; i++) S[i] = 0.f;
}

__global__ __launch_bounds__(256) void convert_bf16(
    const void* __restrict__ src, bf16* __restrict__ dst, int n,
    const int* __restrict__ flag)
{
    const int f = *flag;
    int i = blockIdx.x * 256 + threadIdx.x;
    if (i < n) dst[i] = f2b(ldany(src, i, f));
}

__global__ __launch_bounds__(256) void transpose_any(
    const void* __restrict__ src, bf16* __restrict__ dst,
    int R, int C, const int* __restrict__ flag)
{
    const int f = *flag;
    __shared__ float tile[32][33];
    int tx = threadIdx.x & 31;
    int ty = threadIdx.x >> 5;
    int c0 = blockIdx.x * 32;
    int r0 = blockIdx.y * 32;
    #pragma unroll
    for (int i = 0; i < 4; i++) {
        int r = r0 + ty + i * 8;
        tile[ty + i * 8][tx] = ldany(src, r * C + c0 + tx, f);
    }
    __syncthreads();
    #pragma unroll
    for (int i = 0; i < 4; i++) {
        int cr = c0 + ty + i * 8;
        dst[(size_t)cr * R + r0 + tx] = f2b(tile[tx][ty + i * 8]);
    }
}

// ---------------------------------------------------------------------------
// MFMA GEMM: 128x128 tile, BK=32, 16x16x32 bf16. Bt is N x K row-major, row
// stride Kfull; block covers K-range [blockIdx.z*K, +K) (split-K partials
// stacked at M*N stride, fp32). LDS is XOR-swizzled: logical k-group kg of
// row r lives at physical window kg ^ (r&3) ^ ((r>>2)&3)  ->  fragment
// ds_read_b128 is 2-way-max bank aliasing (free) instead of 4-way.
// ---------------------------------------------------------------------------
__global__ __launch_bounds__(256) void gemm_mfma(
    const bf16* __restrict__ A, const bf16* __restrict__ Bt,
    void* __restrict__ C1v, void* __restrict__ C2v,
    int M, int N, int Kfull, int split,
    const int* __restrict__ flag, int oMode, int K)
{
    const int fo = (oMode == 2) ? 1 : (oMode & *flag);
    __shared__ __align__(16) bf16 As[128 * 32];
    __shared__ __align__(16) bf16 Bs[128 * 32];
    const int tid  = threadIdx.x;
    const int lane = tid & 63;
    const int w    = tid >> 6;
    const int wr   = w & 1, wc = w >> 1;
    const int m0   = blockIdx.y * 128;
    const int n0   = blockIdx.x * 128;
    const int kz   = blockIdx.z;
    const int kst  = kz * K;

    void* C1 = C1v;
    void* C2 = C2v;
    if (kz) { C1 = (char*)C1v + (size_t)kz * M * N * 4; C2 = C1; }

    f32x4 acc[4][4] = {};

    // staging: lane -> row (lane>>2) in its 16-row region, physical window
    // lane&3; global k-group = window ^ swizzle(row)
    const int ldr = lane >> 2;
    const int ldc = ((lane & 3) ^ ((lane >> 2) & 3) ^ ((lane >> 4) & 3)) * 8;
    // fragment read: logical kg = lane>>4, row bits = lane&15
    const int mrow = lane & 15;
    const int qksw = ((lane >> 4) ^ (lane & 3) ^ ((lane >> 2) & 3)) * 8;

    const bf16* aptr[2];
    const bf16* bptr[2];
    #pragma unroll
    for (int j = 0; j < 2; j++) {
        int r = (w * 2 + j) * 16 + ldr;
        aptr[j] = A  + (size_t)(m0 + r) * Kfull + kst + ldc;
        bptr[j] = Bt + (size_t)(n0 + r) * Kfull + kst + ldc;
    }

    for (int it = 0; it < K / 32; it++) {
        __syncthreads();
        #pragma unroll
        for (int j = 0; j < 2; j++) {
            int rg = w * 2 + j;
            load_lds16(aptr[j], (char*)As + rg * 1024);
            load_lds16(bptr[j], (char*)Bs + rg * 1024);
            aptr[j] += 32;
            bptr[j] += 32;
        }
        __syncthreads();

        short8 af[4], bfr[4];
        #pragma unroll
        for (int i = 0; i < 4; i++) {
            af[i]  = *(const short8*)&As[(wr * 64 + i * 16 + mrow) * 32 + qksw];
            bfr[i] = *(const short8*)&Bs[(wc * 64 + i * 16 + mrow) * 32 + qksw];
        }
        #pragma unroll
        for (int mi = 0; mi < 4; mi++)
            #pragma unroll
            for (int ni = 0; ni < 4; ni++)
                acc[mi][ni] = __builtin_amdgcn_mfma_f32_16x16x32_bf16(
                    af[mi], bfr[ni], acc[mi][ni], 0, 0, 0);
    }

    const int orow = m0 + wr * 64 + (lane >> 4) * 4;
    const int ocol = wc * 64 + (lane & 15);

    if (n0 + 128 <= split) {
        if (fo) {
            float* Cp = (float*)C1 + (size_t)orow * split + n0 + ocol;
            #pragma unroll
            for (int mi = 0; mi < 4; mi++)
                #pragma unroll
                for (int ni = 0; ni < 4; ni++)
                    #pragma unroll
                    for (int r = 0; r < 4; r++)
                        Cp[(size_t)(mi * 16 + r) * split + ni * 16] = acc[mi][ni][r];
        } else {
            bf16* Cp = (bf16*)C1 + (size_t)orow * split + n0 + ocol;
            #pragma unroll
            for (int mi = 0; mi < 4; mi++)
                #pragma unroll
                for (int ni = 0; ni < 4; ni++)
                    #pragma unroll
                    for (int r = 0; r < 4; r++)
                        Cp[(size_t)(mi * 16 + r) * split + ni * 16] = f2b(acc[mi][ni][r]);
        }
    } else if (n0 >= split) {
        const int Nc = N - split;
        if (fo) {
            float* Cp = (float*)C2 + (size_t)orow * Nc + (n0 - split) + ocol;
            #pragma unroll
            for (int mi = 0; mi < 4; mi++)
                #pragma unroll
                for (int ni = 0; ni < 4; ni++)
                    #pragma unroll
                    for (int r = 0; r < 4; r++)
                        Cp[(size_t)(mi * 16 + r) * Nc + ni * 16] = acc[mi][ni][r];
        } else {
            bf16* Cp = (bf16*)C2 + (size_t)orow * Nc + (n0 - split) + ocol;
            #pragma unroll
            for (int mi = 0; mi < 4; mi++)
                #pragma unroll
                for (int ni = 0; ni < 4; ni++)
                    #pragma unroll
                    for (int r = 0; r < 4; r++)
                        Cp[(size_t)(mi * 16 + r) * Nc + ni * 16] = f2b(acc[mi][ni][r]);
        }
    } else {
        // narrow tile (xdbl N=33): per-element guard
        #pragma unroll
        for (int mi = 0; mi < 4; mi++)
            #pragma unroll
            for (int ni = 0; ni < 4; ni++)
                #pragma unroll
                for (int r = 0; r < 4; r++) {
                    int row = orow + mi * 16 + r;
                    int col = n0 + ocol + ni * 16;
                    if (col >= N) continue;
                    float v = acc[mi][ni][r];
                    if (col < split) {
                        if (fo) ((float*)C1)[(size_t)row * split + col] = v;
                        else    ((bf16*)C1)[(size_t)row * split + col]  = f2b(v);
                    } else {
                        int c2 = col - split;
                        if (fo) ((float*)C2)[(size_t)row * (N - split) + c2] = v;
                        else    ((bf16*)C2)[(size_t)row * (N - split) + c2]  = f2b(v);
                    }
                }
    }
}

// ---------------------------------------------------------------------------
// Depthwise causal conv (k=4) + bias + SiLU, vectorized (8 d per thread).
// ---------------------------------------------------------------------------
#define CLC 16

__global__ __launch_bounds__(256) void conv_silu_kernel(
    const bf16* __restrict__ x_ssm, const void* __restrict__ conv_w,
    const void* __restrict__ conv_b, bf16* __restrict__ xc,
    const int* __restrict__ flag)
{
    const int f   = *flag;
    const int tid = threadIdx.x;
    const int d0  = tid * 8;
    const int b   = blockIdx.x / (L_SEQ / CLC);
    const int l0  = (blockIdx.x % (L_SEQ / CLC)) * CLC;

    float wk[DCONV][8], bias[8];
    #pragma unroll
    for (int j = 0; j < 8; j++) {
        bias[j] = ldany(conv_b, d0 + j, f);
        #pragma unroll
        for (int k = 0; k < DCONV; k++)
            wk[k][j] = ldany(conv_w, (d0 + j) * DCONV + k, f);
    }

    const size_t rowstr = DINNER;
    const unsigned short* xin = (const unsigned short*)x_ssm;

    float win[3][8];
    #pragma unroll
    for (int r = 0; r < 3; r++) {
        int l = l0 - 3 + r;
        if (l >= 0) {
            V8 v; v.f4 = *(const float4*)(xin + ((size_t)(b * L_SEQ + l)) * rowstr + d0);
            #pragma unroll
            for (int j = 0; j < 8; j++) win[r][j] = us2f(v.us[j]);
        } else {
            #pragma unroll
            for (int j = 0; j < 8; j++) win[r][j] = 0.f;
        }
    }

    #pragma unroll
    for (int t = 0; t < CLC; t++) {
        int l = l0 + t;
        V8 v; v.f4 = *(const float4*)(xin + ((size_t)(b * L_SEQ + l)) * rowstr + d0);
        float cur[8];
        #pragma unroll
        for (int j = 0; j < 8; j++) cur[j] = us2f(v.us[j]);

        V8 o;
        #pragma unroll
        for (int j = 0; j < 8; j++) {
            float s = bias[j];
            s = fmaf(wk[0][j], win[0][j], s);
            s = fmaf(wk[1][j], win[1][j], s);
            s = fmaf(wk[2][j], win[2][j], s);
            s = fmaf(wk[3][j], cur[j],    s);
            float sv = s / (1.f + __expf(-s));
            o.us[j] = (unsigned short)(__bfloat16_as_ushort(f2b(sv)));
        }
        *(float4*)((unsigned short*)xc + ((size_t)(b * L_SEQ + l)) * rowstr + d0) = o.f4;

        #pragma unroll
        for (int j = 0; j < 8; j++) {
            win[0][j] = win[1][j];
            win[1][j] = win[2][j];
            win[2][j] = cur[j];
        }
    }
}

// ---------------------------------------------------------------------------
__global__ void transpose_wx(const void* __restrict__ W_x, bf16* __restrict__ W_xT,
                             const int* __restrict__ flag)
{
    const int f = *flag;
    int idx = blockIdx.x * 256 + threadIdx.x;
    if (idx >= NX * DINNER) return;
    int n = idx / DINNER;
    int k = idx - n * DINNER;
    W_xT[idx] = f2b(ldany(W_x, k * NX + n, f));
}

// ---------------------------------------------------------------------------
// pack P from KSPL stacked xdbl partials; also accumulates per-chunk delta
// sums into S (S zeroed by detect_dtype).
// ---------------------------------------------------------------------------
__global__ __launch_bounds__(256) void pack_P(
    const float* __restrict__ xdbl, const void* __restrict__ A_log,
    float* __restrict__ P, float* __restrict__ S, const int* __restrict__ flag)
{
    const int f = *flag;
    int i  = blockIdx.x * 256 + threadIdx.x;
    int bl = i >> 4, n = i & 15;
    float x0 = 0.f, bn = 0.f, cn = 0.f;
    #pragma unroll
    for (int s = 0; s < KSPL; s++) {
        const float* row = xdbl + (size_t)s * M_ROWS * NX + (size_t)bl * NX;
        x0 += row[0];
        bn += row[1 + n];
        cn += row[17 + n];
    }
    float delta = (x0 > 20.f) ? x0 : log1pf(expf(x0));
    float Aneg = -expf(ldany(A_log, n, f));
    float* p = P + (size_t)bl * PSTR;
    p[n]      = expf(delta * Aneg);
    p[16 + n] = delta * bn;
    p[32 + n] = cn;
    if (n == 0) atomicAdd(&S[bl >> 6], delta);   // bl>>6 == b*NCH + chunk
}

// ---------------------------------------------------------------------------
// Chunked scan. Phase 1: per (b,chunk,d) local scan (h0=0) -> hstate=h_end.
// ---------------------------------------------------------------------------
__global__ __launch_bounds__(256) void scan_phase1(
    const float* __restrict__ P, const bf16* __restrict__ xc,
    float* __restrict__ hstate)
{
    const int blk = blockIdx.x;
    const int b = blk >> 8;
    const int c = (blk >> 3) & 31;
    const int g = blk & 7;
    const int tid = threadIdx.x;
    const int d = g * 256 + tid;

    __shared__ __align__(16) unsigned short sX[CHUNK][256];

    #pragma unroll
    for (int r = 0; r < 16; r++) {
        int i = r * 256 + tid;
        int t = i >> 6;
        int dd = (i & 63) * 4;
        *(ushort4*)&sX[t][dd] = *(const ushort4*)((const unsigned short*)xc +
            ((size_t)(b * L_SEQ) + c * CHUNK + t) * DINNER + g * 256 + dd);
    }
    __syncthreads();

    const float* __restrict__ p = P + ((size_t)(b * L_SEQ) + c * CHUNK) * PSTR;

    float h[16];
    #pragma unroll
    for (int n = 0; n < 16; n++) h[n] = 0.f;

    #pragma unroll 4
    for (int t = 0; t < CHUNK; t++) {
        const float* pt = p + (size_t)t * PSTR;   // wave-uniform
        float4 a0 = *(const float4*)(pt + 0);
        float4 a1 = *(const float4*)(pt + 4);
        float4 a2 = *(const float4*)(pt + 8);
        float4 a3 = *(const float4*)(pt + 12);
        float4 b0 = *(const float4*)(pt + 16);
        float4 b1 = *(const float4*)(pt + 20);
        float4 b2 = *(const float4*)(pt + 24);
        float4 b3 = *(const float4*)(pt + 28);
        float xv = us2f(sX[t][tid]);
        float av[16] = {a0.x,a0.y,a0.z,a0.w, a1.x,a1.y,a1.z,a1.w,
                        a2.x,a2.y,a2.z,a2.w, a3.x,a3.y,a3.z,a3.w};
        float bv[16] = {b0.x,b0.y,b0.z,b0.w, b1.x,b1.y,b1.z,b1.w,
                        b2.x,b2.y,b2.z,b2.w, b3.x,b3.y,b3.z,b3.w};
        #pragma unroll
        for (int n = 0; n < 16; n++)
            h[n] = fmaf(av[n], h[n], bv[n] * xv);
    }
    float* out = hstate + (((size_t)b * NCH + c) * DINNER + d) * 16;
    #pragma unroll
    for (int q = 0; q < 4; q++)
        *(float4*)&out[q * 4] = *(const float4*)&h[q * 4];
}

// ---------------------------------------------------------------------------
__global__ __launch_bounds__(256) void scan_phase2(
    float* __restrict__ hstate, const float* __restrict__ S,
    const void* __restrict__ A_log, const int* __restrict__ flag)
{
    const int f = *flag;
    const int b = blockIdx.x >> 7;
    const int dg = blockIdx.x & 127;
    const int tid = threadIdx.x;
    const int d = dg * 16 + (tid >> 4);
    const int n = tid & 15;
    const float Aneg = -expf(ldany(A_log, n, f));

    __shared__ float sS[NCH];
    if (tid < NCH) sS[tid] = S[b * NCH + tid];
    __syncthreads();

    float H = 0.f;
    size_t base = ((size_t)b * NCH * DINNER + d) * 16 + n;
    for (int c = 0; c < NCH; c++) {
        size_t idx = base + (size_t)c * (DINNER * 16);
        float hend = hstate[idx];
        hstate[idx] = H;
        H = fmaf(__expf(Aneg * sS[c]), H, hend);
    }
}

// ---------------------------------------------------------------------------
// Phase 3: final scan per chunk with correct h_init + fused epilogue.
// ---------------------------------------------------------------------------
__global__ __launch_bounds__(256) void scan_phase3(
    const float* __restrict__ P, const bf16* __restrict__ xc,
    const bf16* __restrict__ z, const void* __restrict__ Dp,
    const float* __restrict__ hstate, bf16* __restrict__ y,
    const int* __restrict__ flag)
{
    const int f = *flag;
    const int blk = blockIdx.x;
    const int b = blk >> 8;
    const int c = (blk >> 3) & 31;
    const int g = blk & 7;
    const int tid = threadIdx.x;
    const int d = g * 256 + tid;

    __shared__ __align__(16) unsigned short sX[CHUNK][256];

    #pragma unroll
    for (int r = 0; r < 16; r++) {
        int i = r * 256 + tid;
        int t = i >> 6;
        int dd = (i & 63) * 4;
        *(ushort4*)&sX[t][dd] = *(const ushort4*)((const unsigned short*)xc +
            ((size_t)(b * L_SEQ) + c * CHUNK + t) * DINNER + g * 256 + dd);
    }
    __syncthreads();

    const float Dd = ldany(Dp, d, f);
    float h[16];
    const float* hin = hstate + (((size_t)b * NCH + c) * DINNER + d) * 16;
    #pragma unroll
    for (int q = 0; q < 4; q++)
        *(float4*)&h[q * 4] = *(const float4*)&hin[q * 4];

    const float* __restrict__ p = P + ((size_t)(b * L_SEQ) + c * CHUNK) * PSTR;
    const size_t ybase = ((size_t)(b * L_SEQ) + c * CHUNK) * DINNER + d;
    const unsigned short* zp = (const unsigned short*)z;

    #pragma unroll 4
    for (int t = 0; t < CHUNK; t++) {
        const float* pt = p + (size_t)t * PSTR;   // wave-uniform
        float4 a0 = *(const float4*)(pt + 0);
        float4 a1 = *(const float4*)(pt + 4);
        float4 a2 = *(const float4*)(pt + 8);
        float4 a3 = *(const float4*)(pt + 12);
        float4 b0 = *(const float4*)(pt + 16);
        float4 b1 = *(const float4*)(pt + 20);
        float4 b2 = *(const float4*)(pt + 24);
        float4 b3 = *(const float4*)(pt + 28);
        float4 c0 = *(const float4*)(pt + 32);
        float4 c1 = *(const float4*)(pt + 36);
        float4 c2 = *(const float4*)(pt + 40);
        float4 c3 = *(const float4*)(pt + 44);
        float xv = us2f(sX[t][tid]);
        float av[16] = {a0.x,a0.y,a0.z,a0.w, a1.x,a1.y,a1.z,a1.w,
                        a2.x,a2.y,a2.z,a2.w, a3.x,a3.y,a3.z,a3.w};
        float bv[16] = {b0.x,b0.y,b0.z,b0.w, b1.x,b1.y,b1.z,b1.w,
                        b2.x,b2.y,b2.z,b2.w, b3.x,b3.y,b3.z,b3.w};
        float cv[16] = {c0.x,c0.y,c0.z,c0.w, c1.x,c1.y,c1.z,c1.w,
                        c2.x,c2.y,c2.z,c2.w, c3.x,c3.y,c3.z,c3.w};
        float p0 = 0.f, p1 = 0.f;
        #pragma unroll
        for (int n = 0; n < 16; n += 2) {
            h[n]     = fmaf(av[n],     h[n],     bv[n]     * xv);
            h[n + 1] = fmaf(av[n + 1], h[n + 1], bv[n + 1] * xv);
            p0 = fmaf(h[n],     cv[n],     p0);
            p1 = fmaf(h[n + 1], cv[n + 1], p1);
        }
        float zv = us2f(zp[ybase + (size_t)t * DINNER]);
        float yv = (p0 + p1) + xv * Dd;
        float sz = zv / (1.f + __expf(-zv));
        y[ybase + (size_t)t * DINNER] = f2b(yv * sz);
    }
}

// ---------------------------------------------------------------------------
extern "C" void kernel_launch(void* const* d_in, const int* in_sizes, int n_in,
                              void* d_out, int out_size, void* d_ws, size_t ws_size,
                              hipStream_t stream)
{
    const void* x      = d_in[0];
    const void* W_in   = d_in[1];
    const void* conv_w = d_in[2];
    const void* conv_b = d_in[3];
    const void* W_x    = d_in[4];
    const void* A_log  = d_in[5];
    const void* Dp     = d_in[6];
    const void* W_out  = d_in[7];

    char* w = (char*)d_ws;
    bf16* x_ssm = (bf16*)w; w += (size_t)M_ROWS * DINNER * 2;   // 32 MB slot
    bf16* z     = (bf16*)w; w += (size_t)M_ROWS * DINNER * 2;
    bf16* xc    = (bf16*)w; w += (size_t)M_ROWS * DINNER * 2;
    bf16* yb    = (bf16*)w; w += (size_t)M_ROWS * DINNER * 2;
    float* P    = (float*)w; w += (size_t)M_ROWS * PSTR * 4;    // 1.7 MB
    int*  flag  = (int*)w;  w += 256;
    float* S    = (float*)w; w += 4096;

    // Aliases (lifetime-checked against pipeline order):
    bf16* x_bf    = yb;                       // dead after GEMM1
    bf16* W_inT   = xc;                       // dead after GEMM1; conv writes xc
    bf16* W_outT  = x_ssm;                    // 4 MB, after conv consumed x_ssm
    float* hstate = (float*)((char*)x_ssm + (size_t)DMODEL * DINNER * 2); // +16.8 MB
    // xdbl partials (KSPL x 8192 x 33 fp32 = 8.65 MB) at yb; padded W_xT
    // (128 x 2048 bf16 = 512 KB) at yb+12MB. Both written after GEMM1 (x_bf
    // dead), dead before scan_phase3 overwrites yb.
    float* xdbl  = (float*)yb;
    bf16*  W_xT  = (bf16*)((char*)yb + 12 * 1024 * 1024);

    detect_dtype<<<1, 1, 0, stream>>>((const unsigned int*)A_log, flag, S);

    // pre-convert
    convert_bf16<<<(M_ROWS * DMODEL) / 256, 256, 0, stream>>>(x, x_bf, M_ROWS * DMODEL, flag);
    transpose_any<<<dim3((2 * DINNER) / 32, DMODEL / 32), 256, 0, stream>>>(
        W_in, W_inT, DMODEL, 2 * DINNER, flag);

    // GEMM1: xz = x @ W_in -> x_ssm | z
    gemm_mfma<<<dim3((2 * DINNER) / 128, M_ROWS / 128), 256, 0, stream>>>(
        x_bf, W_inT, x_ssm, z, M_ROWS, 2 * DINNER, DMODEL, DINNER, flag, 0, DMODEL);

    // conv + SiLU
    conv_silu_kernel<<<BATCH * (L_SEQ / CLC), 256, 0, stream>>>(
        x_ssm, conv_w, conv_b, xc, flag);

    // W_out^T into freed x_ssm slot
    transpose_any<<<dim3(DMODEL / 32, DINNER / 32), 256, 0, stream>>>(
        W_out, W_outT, DINNER, DMODEL, flag);

    // x_dbl = xc @ W_x via split-K MFMA (grid.z = KSPL), then pack P (+S)
    transpose_wx<<<(NX * DINNER + 255) / 256, 256, 0, stream>>>(W_x, W_xT, flag);
    gemm_mfma<<<dim3(1, M_ROWS / 128, KSPL), 256, 0, stream>>>(
        xc, W_xT, xdbl, xdbl, M_ROWS, NX, DINNER, NX, flag, 2, DINNER / KSPL);
    pack_P<<<(M_ROWS * 16) / 256, 256, 0, stream>>>(xdbl, A_log, P, S, flag);

    // chunked scan
    scan_phase1<<<BATCH * NCH * 8, 256, 0, stream>>>(P, xc, hstate);
    scan_phase2<<<BATCH * 128, 256, 0, stream>>>(hstate, S, A_log, flag);
    scan_phase3<<<BATCH * NCH * 8, 256, 0, stream>>>(P, xc, z, Dp, hstate, yb, flag);

    // GEMM2: out = y @ W_out
    gemm_mfma<<<dim3(DMODEL / 128, M_ROWS / 128), 256, 0, stream>>>(
        yb, W_outT, d_out, d_out, M_ROWS, DMODEL, DINNER, DMODEL, flag, 1, DINNER);
}

// Round 9
// 387.911 us; speedup vs baseline: 1.1107x; 1.1107x over previous
//
#include <hip/hip_runtime.h>
#include <hip/hip_bf16.h>
#include <math.h>

typedef __hip_bfloat16 bf16;
typedef __attribute__((ext_vector_type(8))) short short8;
typedef __attribute__((ext_vector_type(4))) float f32x4;

#define BATCH   4
#define L_SEQ   2048
#define DMODEL  1024
#define DSTATE  16
#define DCONV   4
#define DINNER  2048
#define M_ROWS  (BATCH * L_SEQ)   // 8192

#define CHUNK   64
#define NCH     (L_SEQ / CHUNK)   // 32
#define PSTR    52                // P record: A_bar[16] B_bar[16] C[16] delta pad3 (208B)
#define NX      33                // x_dbl columns
#define KSPL    4                 // K-split for the xdbl GEMM

__device__ __forceinline__ float b2f(bf16 v) { return __bfloat162float(v); }
__device__ __forceinline__ bf16  f2b(float v) { return __float2bfloat16(v); }
__device__ __forceinline__ float us2f(unsigned short u) {
    return __uint_as_float(((unsigned)u) << 16);
}
__device__ __forceinline__ float ldany(const void* p, int i, int f32) {
    return f32 ? ((const float*)p)[i] : b2f(((const bf16*)p)[i]);
}
__device__ __forceinline__ void load_lds16(const void* g, void* l) {
    __builtin_amdgcn_global_load_lds(
        (const __attribute__((address_space(1))) unsigned int*)g,
        (__attribute__((address_space(3))) unsigned int*)l, 16, 0, 0);
}

union V8 { float4 f4; unsigned short us[8]; };

// ---------------------------------------------------------------------------
__global__ void detect_dtype(const unsigned int* __restrict__ alog_bits,
                             int* __restrict__ flag)
{
    *flag = (alog_bits[0] == 0u) ? 1 : 0;
}

__global__ __launch_bounds__(256) void convert_bf16(
    const void* __restrict__ src, bf16* __restrict__ dst, int n,
    const int* __restrict__ flag)
{
    const int f = *flag;
    int i = blockIdx.x * 256 + threadIdx.x;
    if (i < n) dst[i] = f2b(ldany(src, i, f));
}

__global__ __launch_bounds__(256) void transpose_any(
    const void* __restrict__ src, bf16* __restrict__ dst,
    int R, int C, const int* __restrict__ flag)
{
    const int f = *flag;
    __shared__ float tile[32][33];
    int tx = threadIdx.x & 31;
    int ty = threadIdx.x >> 5;
    int c0 = blockIdx.x * 32;
    int r0 = blockIdx.y * 32;
    #pragma unroll
    for (int i = 0; i < 4; i++) {
        int r = r0 + ty + i * 8;
        tile[ty + i * 8][tx] = ldany(src, r * C + c0 + tx, f);
    }
    __syncthreads();
    #pragma unroll
    for (int i = 0; i < 4; i++) {
        int cr = c0 + ty + i * 8;
        dst[(size_t)cr * R + r0 + tx] = f2b(tile[tx][ty + i * 8]);
    }
}

// ---------------------------------------------------------------------------
// MFMA GEMM: 128x128 tile, BK=32, 16x16x32 bf16, DOUBLE-BUFFERED staging:
// iter it prefetches it+1's tiles (async global_load_lds) before the MFMA
// burst; single barrier per iter. XOR-swizzled LDS k-windows (kept from R8).
// Bt is N x K row-major, stride Kfull; block covers K-range [bz*K, +K);
// split-K partials stacked at M*N (fp32). oMode: 0=bf16, 1=follow flag, 2=fp32.
// ---------------------------------------------------------------------------
__global__ __launch_bounds__(256) void gemm_mfma(
    const bf16* __restrict__ A, const bf16* __restrict__ Bt,
    void* __restrict__ C1v, void* __restrict__ C2v,
    int M, int N, int Kfull, int split,
    const int* __restrict__ flag, int oMode, int K)
{
    const int fo = (oMode == 2) ? 1 : (oMode & *flag);
    __shared__ __align__(16) bf16 As[2][128 * 32];
    __shared__ __align__(16) bf16 Bs[2][128 * 32];
    const int tid  = threadIdx.x;
    const int lane = tid & 63;
    const int w    = tid >> 6;
    const int wr   = w & 1, wc = w >> 1;
    const int m0   = blockIdx.y * 128;
    const int n0   = blockIdx.x * 128;
    const int kz   = blockIdx.z;
    const int kst  = kz * K;

    void* C1 = C1v;
    void* C2 = C2v;
    if (kz) { C1 = (char*)C1v + (size_t)kz * M * N * 4; C2 = C1; }

    f32x4 acc[4][4] = {};

    const int ldr  = lane >> 2;
    const int ldc  = ((lane & 3) ^ ((lane >> 2) & 3) ^ ((lane >> 4) & 3)) * 8;
    const int mrow = lane & 15;
    const int qksw = ((lane >> 4) ^ (lane & 3) ^ ((lane >> 2) & 3)) * 8;

    const bf16* aptr[2];
    const bf16* bptr[2];
    #pragma unroll
    for (int j = 0; j < 2; j++) {
        int r = (w * 2 + j) * 16 + ldr;
        aptr[j] = A  + (size_t)(m0 + r) * Kfull + kst + ldc;
        bptr[j] = Bt + (size_t)(n0 + r) * Kfull + kst + ldc;
    }

    const int iters = K / 32;
    // prologue: stage iter 0 into buffer 0
    #pragma unroll
    for (int j = 0; j < 2; j++) {
        int rg = w * 2 + j;
        load_lds16(aptr[j], (char*)As[0] + rg * 1024);
        load_lds16(bptr[j], (char*)Bs[0] + rg * 1024);
        aptr[j] += 32;
        bptr[j] += 32;
    }
    __syncthreads();

    for (int it = 0; it < iters; it++) {
        const int cur = it & 1;
        if (it + 1 < iters) {
            const int nxt = cur ^ 1;
            #pragma unroll
            for (int j = 0; j < 2; j++) {
                int rg = w * 2 + j;
                load_lds16(aptr[j], (char*)As[nxt] + rg * 1024);
                load_lds16(bptr[j], (char*)Bs[nxt] + rg * 1024);
                aptr[j] += 32;
                bptr[j] += 32;
            }
        }
        short8 af[4], bfr[4];
        #pragma unroll
        for (int i = 0; i < 4; i++) {
            af[i]  = *(const short8*)&As[cur][(wr * 64 + i * 16 + mrow) * 32 + qksw];
            bfr[i] = *(const short8*)&Bs[cur][(wc * 64 + i * 16 + mrow) * 32 + qksw];
        }
        #pragma unroll
        for (int mi = 0; mi < 4; mi++)
            #pragma unroll
            for (int ni = 0; ni < 4; ni++)
                acc[mi][ni] = __builtin_amdgcn_mfma_f32_16x16x32_bf16(
                    af[mi], bfr[ni], acc[mi][ni], 0, 0, 0);
        __syncthreads();   // drains prefetch (issued ~MFMA-burst earlier) + read-fence
    }

    const int orow = m0 + wr * 64 + (lane >> 4) * 4;
    const int ocol = wc * 64 + (lane & 15);

    if (n0 + 128 <= split) {
        if (fo) {
            float* Cp = (float*)C1 + (size_t)orow * split + n0 + ocol;
            #pragma unroll
            for (int mi = 0; mi < 4; mi++)
                #pragma unroll
                for (int ni = 0; ni < 4; ni++)
                    #pragma unroll
                    for (int r = 0; r < 4; r++)
                        Cp[(size_t)(mi * 16 + r) * split + ni * 16] = acc[mi][ni][r];
        } else {
            bf16* Cp = (bf16*)C1 + (size_t)orow * split + n0 + ocol;
            #pragma unroll
            for (int mi = 0; mi < 4; mi++)
                #pragma unroll
                for (int ni = 0; ni < 4; ni++)
                    #pragma unroll
                    for (int r = 0; r < 4; r++)
                        Cp[(size_t)(mi * 16 + r) * split + ni * 16] = f2b(acc[mi][ni][r]);
        }
    } else if (n0 >= split) {
        const int Nc = N - split;
        if (fo) {
            float* Cp = (float*)C2 + (size_t)orow * Nc + (n0 - split) + ocol;
            #pragma unroll
            for (int mi = 0; mi < 4; mi++)
                #pragma unroll
                for (int ni = 0; ni < 4; ni++)
                    #pragma unroll
                    for (int r = 0; r < 4; r++)
                        Cp[(size_t)(mi * 16 + r) * Nc + ni * 16] = acc[mi][ni][r];
        } else {
            bf16* Cp = (bf16*)C2 + (size_t)orow * Nc + (n0 - split) + ocol;
            #pragma unroll
            for (int mi = 0; mi < 4; mi++)
                #pragma unroll
                for (int ni = 0; ni < 4; ni++)
                    #pragma unroll
                    for (int r = 0; r < 4; r++)
                        Cp[(size_t)(mi * 16 + r) * Nc + ni * 16] = f2b(acc[mi][ni][r]);
        }
    } else {
        // narrow tile (xdbl N=33): per-element guard
        #pragma unroll
        for (int mi = 0; mi < 4; mi++)
            #pragma unroll
            for (int ni = 0; ni < 4; ni++)
                #pragma unroll
                for (int r = 0; r < 4; r++) {
                    int row = orow + mi * 16 + r;
                    int col = n0 + ocol + ni * 16;
                    if (col >= N) continue;
                    float v = acc[mi][ni][r];
                    if (col < split) {
                        if (fo) ((float*)C1)[(size_t)row * split + col] = v;
                        else    ((bf16*)C1)[(size_t)row * split + col]  = f2b(v);
                    } else {
                        int c2 = col - split;
                        if (fo) ((float*)C2)[(size_t)row * (N - split) + c2] = v;
                        else    ((bf16*)C2)[(size_t)row * (N - split) + c2]  = f2b(v);
                    }
                }
    }
}

// ---------------------------------------------------------------------------
// Depthwise causal conv (k=4) + bias + SiLU, vectorized (8 d per thread).
// ---------------------------------------------------------------------------
#define CLC 16

__global__ __launch_bounds__(256) void conv_silu_kernel(
    const bf16* __restrict__ x_ssm, const void* __restrict__ conv_w,
    const void* __restrict__ conv_b, bf16* __restrict__ xc,
    const int* __restrict__ flag)
{
    const int f   = *flag;
    const int tid = threadIdx.x;
    const int d0  = tid * 8;
    const int b   = blockIdx.x / (L_SEQ / CLC);
    const int l0  = (blockIdx.x % (L_SEQ / CLC)) * CLC;

    float wk[DCONV][8], bias[8];
    #pragma unroll
    for (int j = 0; j < 8; j++) {
        bias[j] = ldany(conv_b, d0 + j, f);
        #pragma unroll
        for (int k = 0; k < DCONV; k++)
            wk[k][j] = ldany(conv_w, (d0 + j) * DCONV + k, f);
    }

    const size_t rowstr = DINNER;
    const unsigned short* xin = (const unsigned short*)x_ssm;

    float win[3][8];
    #pragma unroll
    for (int r = 0; r < 3; r++) {
        int l = l0 - 3 + r;
        if (l >= 0) {
            V8 v; v.f4 = *(const float4*)(xin + ((size_t)(b * L_SEQ + l)) * rowstr + d0);
            #pragma unroll
            for (int j = 0; j < 8; j++) win[r][j] = us2f(v.us[j]);
        } else {
            #pragma unroll
            for (int j = 0; j < 8; j++) win[r][j] = 0.f;
        }
    }

    #pragma unroll
    for (int t = 0; t < CLC; t++) {
        int l = l0 + t;
        V8 v; v.f4 = *(const float4*)(xin + ((size_t)(b * L_SEQ + l)) * rowstr + d0);
        float cur[8];
        #pragma unroll
        for (int j = 0; j < 8; j++) cur[j] = us2f(v.us[j]);

        V8 o;
        #pragma unroll
        for (int j = 0; j < 8; j++) {
            float s = bias[j];
            s = fmaf(wk[0][j], win[0][j], s);
            s = fmaf(wk[1][j], win[1][j], s);
            s = fmaf(wk[2][j], win[2][j], s);
            s = fmaf(wk[3][j], cur[j],    s);
            float sv = s / (1.f + __expf(-s));
            o.us[j] = (unsigned short)(__bfloat16_as_ushort(f2b(sv)));
        }
        *(float4*)((unsigned short*)xc + ((size_t)(b * L_SEQ + l)) * rowstr + d0) = o.f4;

        #pragma unroll
        for (int j = 0; j < 8; j++) {
            win[0][j] = win[1][j];
            win[1][j] = win[2][j];
            win[2][j] = cur[j];
        }
    }
}

// ---------------------------------------------------------------------------
__global__ void transpose_wx(const void* __restrict__ W_x, bf16* __restrict__ W_xT,
                             const int* __restrict__ flag)
{
    const int f = *flag;
    int idx = blockIdx.x * 256 + threadIdx.x;
    if (idx >= NX * DINNER) return;
    int n = idx / DINNER;
    int k = idx - n * DINNER;
    W_xT[idx] = f2b(ldany(W_x, k * NX + n, f));
}

// ---------------------------------------------------------------------------
// pack P from KSPL stacked xdbl partials:
// P[bl][52] = {A_bar[16], B_bar[16], C[16], delta, pad3}
// ---------------------------------------------------------------------------
__global__ __launch_bounds__(256) void pack_P(
    const float* __restrict__ xdbl, const void* __restrict__ A_log,
    float* __restrict__ P, const int* __restrict__ flag)
{
    const int f = *flag;
    int i  = blockIdx.x * 256 + threadIdx.x;
    int bl = i >> 4, n = i & 15;
    float x0 = 0.f, bn = 0.f, cn = 0.f;
    #pragma unroll
    for (int s = 0; s < KSPL; s++) {
        const float* row = xdbl + (size_t)s * M_ROWS * NX + (size_t)bl * NX;
        x0 += row[0];
        bn += row[1 + n];
        cn += row[17 + n];
    }
    float delta = (x0 > 20.f) ? x0 : log1pf(expf(x0));
    float Aneg = -expf(ldany(A_log, n, f));
    float* p = P + (size_t)bl * PSTR;
    p[n]      = expf(delta * Aneg);
    p[16 + n] = delta * bn;
    p[32 + n] = cn;
    if (n == 0) p[48] = delta;
}

// ---------------------------------------------------------------------------
// Chunked scan. Phase 1: per (b,chunk,d) local scan (h0=0) -> hstate=h_end.
// ---------------------------------------------------------------------------
__global__ __launch_bounds__(256) void scan_phase1(
    const float* __restrict__ P, const bf16* __restrict__ xc,
    float* __restrict__ hstate)
{
    const int blk = blockIdx.x;
    const int b = blk >> 8;
    const int c = (blk >> 3) & 31;
    const int g = blk & 7;
    const int tid = threadIdx.x;
    const int d = g * 256 + tid;

    __shared__ __align__(16) unsigned short sX[CHUNK][256];

    #pragma unroll
    for (int r = 0; r < 16; r++) {
        int i = r * 256 + tid;
        int t = i >> 6;
        int dd = (i & 63) * 4;
        *(ushort4*)&sX[t][dd] = *(const ushort4*)((const unsigned short*)xc +
            ((size_t)(b * L_SEQ) + c * CHUNK + t) * DINNER + g * 256 + dd);
    }
    __syncthreads();

    const float* __restrict__ p = P + ((size_t)(b * L_SEQ) + c * CHUNK) * PSTR;

    float h[16];
    #pragma unroll
    for (int n = 0; n < 16; n++) h[n] = 0.f;

    #pragma unroll 4
    for (int t = 0; t < CHUNK; t++) {
        const float* pt = p + (size_t)t * PSTR;   // wave-uniform
        float4 a0 = *(const float4*)(pt + 0);
        float4 a1 = *(const float4*)(pt + 4);
        float4 a2 = *(const float4*)(pt + 8);
        float4 a3 = *(const float4*)(pt + 12);
        float4 b0 = *(const float4*)(pt + 16);
        float4 b1 = *(const float4*)(pt + 20);
        float4 b2 = *(const float4*)(pt + 24);
        float4 b3 = *(const float4*)(pt + 28);
        float xv = us2f(sX[t][tid]);
        float av[16] = {a0.x,a0.y,a0.z,a0.w, a1.x,a1.y,a1.z,a1.w,
                        a2.x,a2.y,a2.z,a2.w, a3.x,a3.y,a3.z,a3.w};
        float bv[16] = {b0.x,b0.y,b0.z,b0.w, b1.x,b1.y,b1.z,b1.w,
                        b2.x,b2.y,b2.z,b2.w, b3.x,b3.y,b3.z,b3.w};
        #pragma unroll
        for (int n = 0; n < 16; n++)
            h[n] = fmaf(av[n], h[n], bv[n] * xv);
    }
    float* out = hstate + (((size_t)b * NCH + c) * DINNER + d) * 16;
    #pragma unroll
    for (int q = 0; q < 4; q++)
        *(float4*)&out[q * 4] = *(const float4*)&h[q * 4];
}

// ---------------------------------------------------------------------------
// S[b][c] = sum of delta over chunk c. 128 blocks x 1 wave.
// ---------------------------------------------------------------------------
__global__ __launch_bounds__(64) void sum_delta(const float* __restrict__ P,
                                                float* __restrict__ S)
{
    int i = blockIdx.x;           // b*NCH + c
    int t = threadIdx.x;          // 0..63
    float v = P[((size_t)((i >> 5) * L_SEQ) + (i & 31) * CHUNK + t) * PSTR + 48];
    #pragma unroll
    for (int off = 32; off > 0; off >>= 1)
        v += __shfl_xor(v, off);
    if (t == 0) S[i] = v;
}

// ---------------------------------------------------------------------------
__global__ __launch_bounds__(256) void scan_phase2(
    float* __restrict__ hstate, const float* __restrict__ S,
    const void* __restrict__ A_log, const int* __restrict__ flag)
{
    const int f = *flag;
    const int b = blockIdx.x >> 7;
    const int dg = blockIdx.x & 127;
    const int tid = threadIdx.x;
    const int d = dg * 16 + (tid >> 4);
    const int n = tid & 15;
    const float Aneg = -expf(ldany(A_log, n, f));

    __shared__ float sS[NCH];
    if (tid < NCH) sS[tid] = S[b * NCH + tid];
    __syncthreads();

    float H = 0.f;
    size_t base = ((size_t)b * NCH * DINNER + d) * 16 + n;
    for (int c = 0; c < NCH; c++) {
        size_t idx = base + (size_t)c * (DINNER * 16);
        float hend = hstate[idx];
        hstate[idx] = H;
        H = fmaf(__expf(Aneg * sS[c]), H, hend);
    }
}

// ---------------------------------------------------------------------------
// Phase 3: final scan per chunk with correct h_init + fused epilogue.
// ---------------------------------------------------------------------------
__global__ __launch_bounds__(256) void scan_phase3(
    const float* __restrict__ P, const bf16* __restrict__ xc,
    const bf16* __restrict__ z, const void* __restrict__ Dp,
    const float* __restrict__ hstate, bf16* __restrict__ y,
    const int* __restrict__ flag)
{
    const int f = *flag;
    const int blk = blockIdx.x;
    const int b = blk >> 8;
    const int c = (blk >> 3) & 31;
    const int g = blk & 7;
    const int tid = threadIdx.x;
    const int d = g * 256 + tid;

    __shared__ __align__(16) unsigned short sX[CHUNK][256];

    #pragma unroll
    for (int r = 0; r < 16; r++) {
        int i = r * 256 + tid;
        int t = i >> 6;
        int dd = (i & 63) * 4;
        *(ushort4*)&sX[t][dd] = *(const ushort4*)((const unsigned short*)xc +
            ((size_t)(b * L_SEQ) + c * CHUNK + t) * DINNER + g * 256 + dd);
    }
    __syncthreads();

    const float Dd = ldany(Dp, d, f);
    float h[16];
    const float* hin = hstate + (((size_t)b * NCH + c) * DINNER + d) * 16;
    #pragma unroll
    for (int q = 0; q < 4; q++)
        *(float4*)&h[q * 4] = *(const float4*)&hin[q * 4];

    const float* __restrict__ p = P + ((size_t)(b * L_SEQ) + c * CHUNK) * PSTR;
    const size_t ybase = ((size_t)(b * L_SEQ) + c * CHUNK) * DINNER + d;
    const unsigned short* zp = (const unsigned short*)z;

    #pragma unroll 4
    for (int t = 0; t < CHUNK; t++) {
        const float* pt = p + (size_t)t * PSTR;   // wave-uniform
        float4 a0 = *(const float4*)(pt + 0);
        float4 a1 = *(const float4*)(pt + 4);
        float4 a2 = *(const float4*)(pt + 8);
        float4 a3 = *(const float4*)(pt + 12);
        float4 b0 = *(const float4*)(pt + 16);
        float4 b1 = *(const float4*)(pt + 20);
        float4 b2 = *(const float4*)(pt + 24);
        float4 b3 = *(const float4*)(pt + 28);
        float4 c0 = *(const float4*)(pt + 32);
        float4 c1 = *(const float4*)(pt + 36);
        float4 c2 = *(const float4*)(pt + 40);
        float4 c3 = *(const float4*)(pt + 44);
        float xv = us2f(sX[t][tid]);
        float av[16] = {a0.x,a0.y,a0.z,a0.w, a1.x,a1.y,a1.z,a1.w,
                        a2.x,a2.y,a2.z,a2.w, a3.x,a3.y,a3.z,a3.w};
        float bv[16] = {b0.x,b0.y,b0.z,b0.w, b1.x,b1.y,b1.z,b1.w,
                        b2.x,b2.y,b2.z,b2.w, b3.x,b3.y,b3.z,b3.w};
        float cv[16] = {c0.x,c0.y,c0.z,c0.w, c1.x,c1.y,c1.z,c1.w,
                        c2.x,c2.y,c2.z,c2.w, c3.x,c3.y,c3.z,c3.w};
        float p0 = 0.f, p1 = 0.f;
        #pragma unroll
        for (int n = 0; n < 16; n += 2) {
            h[n]     = fmaf(av[n],     h[n],     bv[n]     * xv);
            h[n + 1] = fmaf(av[n + 1], h[n + 1], bv[n + 1] * xv);
            p0 = fmaf(h[n],     cv[n],     p0);
            p1 = fmaf(h[n + 1], cv[n + 1], p1);
        }
        float zv = us2f(zp[ybase + (size_t)t * DINNER]);
        float yv = (p0 + p1) + xv * Dd;
        float sz = zv / (1.f + __expf(-zv));
        y[ybase + (size_t)t * DINNER] = f2b(yv * sz);
    }
}

// ---------------------------------------------------------------------------
extern "C" void kernel_launch(void* const* d_in, const int* in_sizes, int n_in,
                              void* d_out, int out_size, void* d_ws, size_t ws_size,
                              hipStream_t stream)
{
    const void* x      = d_in[0];
    const void* W_in   = d_in[1];
    const void* conv_w = d_in[2];
    const void* conv_b = d_in[3];
    const void* W_x    = d_in[4];
    const void* A_log  = d_in[5];
    const void* Dp     = d_in[6];
    const void* W_out  = d_in[7];

    char* w = (char*)d_ws;
    bf16* x_ssm = (bf16*)w; w += (size_t)M_ROWS * DINNER * 2;   // 32 MB slot
    bf16* z     = (bf16*)w; w += (size_t)M_ROWS * DINNER * 2;
    bf16* xc    = (bf16*)w; w += (size_t)M_ROWS * DINNER * 2;
    bf16* yb    = (bf16*)w; w += (size_t)M_ROWS * DINNER * 2;
    float* P    = (float*)w; w += (size_t)M_ROWS * PSTR * 4;    // 1.7 MB
    int*  flag  = (int*)w;  w += 256;
    float* S    = (float*)w; w += 4096;

    // Aliases (lifetime-checked against pipeline order):
    bf16* x_bf    = yb;                       // dead after GEMM1
    bf16* W_inT   = xc;                       // dead after GEMM1; conv writes xc
    bf16* W_outT  = x_ssm;                    // 4 MB, after conv consumed x_ssm
    float* hstate = (float*)((char*)x_ssm + (size_t)DMODEL * DINNER * 2); // +16.8 MB
    // xdbl partials (KSPL x 8192 x 33 fp32 = 4.3 MB) at yb; padded W_xT
    // (128 x 2048 bf16 = 512 KB) at yb+8MB. Both written after GEMM1 (x_bf
    // dead), dead before scan_phase3 overwrites yb.
    float* xdbl  = (float*)yb;
    bf16*  W_xT  = (bf16*)((char*)yb + 8 * 1024 * 1024);

    detect_dtype<<<1, 1, 0, stream>>>((const unsigned int*)A_log, flag);

    // pre-convert
    convert_bf16<<<(M_ROWS * DMODEL) / 256, 256, 0, stream>>>(x, x_bf, M_ROWS * DMODEL, flag);
    transpose_any<<<dim3((2 * DINNER) / 32, DMODEL / 32), 256, 0, stream>>>(
        W_in, W_inT, DMODEL, 2 * DINNER, flag);

    // GEMM1: xz = x @ W_in -> x_ssm | z
    gemm_mfma<<<dim3((2 * DINNER) / 128, M_ROWS / 128), 256, 0, stream>>>(
        x_bf, W_inT, x_ssm, z, M_ROWS, 2 * DINNER, DMODEL, DINNER, flag, 0, DMODEL);

    // conv + SiLU
    conv_silu_kernel<<<BATCH * (L_SEQ / CLC), 256, 0, stream>>>(
        x_ssm, conv_w, conv_b, xc, flag);

    // W_out^T into freed x_ssm slot
    transpose_any<<<dim3(DMODEL / 32, DINNER / 32), 256, 0, stream>>>(
        W_out, W_outT, DINNER, DMODEL, flag);

    // x_dbl = xc @ W_x via split-K MFMA (grid.z = KSPL), then pack P
    transpose_wx<<<(NX * DINNER + 255) / 256, 256, 0, stream>>>(W_x, W_xT, flag);
    gemm_mfma<<<dim3(1, M_ROWS / 128, KSPL), 256, 0, stream>>>(
        xc, W_xT, xdbl, xdbl, M_ROWS, NX, DINNER, NX, flag, 2, DINNER / KSPL);
    pack_P<<<(M_ROWS * 16) / 256, 256, 0, stream>>>(xdbl, A_log, P, flag);

    // chunked scan
    scan_phase1<<<BATCH * NCH * 8, 256, 0, stream>>>(P, xc, hstate);
    sum_delta<<<BATCH * NCH, 64, 0, stream>>>(P, S);
    scan_phase2<<<BATCH * 128, 256, 0, stream>>>(hstate, S, A_log, flag);
    scan_phase3<<<BATCH * NCH * 8, 256, 0, stream>>>(P, xc, z, Dp, hstate, yb, flag);

    // GEMM2: out = y @ W_out
    gemm_mfma<<<dim3(DMODEL / 128, M_ROWS / 128), 256, 0, stream>>>(
        yb, W_outT, d_out, d_out, M_ROWS, DMODEL, DINNER, DMODEL, flag, 1, DINNER);
}